// Round 10
// baseline (320.103 us; speedup 1.0000x reference)
//
#include <hip/hip_runtime.h>
#include <hip/hip_bf16.h>
#include <stdint.h>

typedef unsigned short u16;
typedef uint32_t u32;
typedef uint64_t u64;

#define NB 2
#define NA 8732
#define ND 604
#define NC 599
#define NM 300
#define NK 200
#define MT (NC * NM)     // 179700
#define NA4 (NA / 4)     // 2183
#define CONF 0.01f
#define NBIN 4096

#define T_PRESET (0xFull << 40)

__device__ __forceinline__ float bf2f(u16 u) { return __uint_as_float(((u32)u) << 16); }

// global top-k bin: fine resolution near s=1 (kept scores concentrate in (0.966,1)).
// bin ASCENDS as score DESCENDS.
__device__ __forceinline__ u32 binTop(u32 sbits) {
  const float t = __fsub_rn(1.0f, __uint_as_float(sbits));
  const float u = __fmul_rn(t, 65536.0f);
  u32 bin = (u32)u;
  return bin > (NBIN - 1) ? (NBIN - 1) : bin;
}

// per-class coarse score bin (ascending in score)
__device__ __forceinline__ u32 bin8(u32 kbits) {
  u32 bin = (u32)__fmul_rn(__uint_as_float(kbits), 256.0f);
  return bin > 255 ? 255 : bin;
}

// meta[0] = input storage is true-bf16. Also zeroes the per-batch score histogram.
__global__ void k_detect(const u16* __restrict__ in, u32* __restrict__ meta,
                         u32* __restrict__ hist) {
  __shared__ u32 ws4[4], wz4[4];
  const int tid = threadIdx.x, lane = tid & 63, wid = tid >> 6;
  u32 ct = 0, cz = 0;
  for (int i = tid; i < 8192; i += 256) {
    const u16 v = in[i];
    ct += (u32)(v >> 15);
    cz += (u32)(((i & 1) == 0) && (v == 0));
  }
  for (int i = tid; i < NB * NBIN; i += 256) hist[i] = 0u;
#pragma unroll
  for (int off = 32; off > 0; off >>= 1) {
    ct += __shfl_down(ct, off, 64);
    cz += __shfl_down(cz, off, 64);
  }
  if (lane == 0) { ws4[wid] = ct; wz4[wid] = cz; }
  __syncthreads();
  if (tid == 0) {
    const u32 tot_top = ws4[0] + ws4[1] + ws4[2] + ws4[3];
    const u32 tot_evz = wz4[0] + wz4[1] + wz4[2] + wz4[3];
    meta[0] = (tot_top == 0 && tot_evz < 1024) ? 1u : 0u;  // else f32 storage
    meta[1] = 0u; meta[2] = 0u; meta[3] = 0u;
  }
}

// tiled transpose of class scores -> thresholded u32 keys [b][c][n]
__global__ __launch_bounds__(256) void k_transpose_keys(const void* __restrict__ inv,
                                                        const u32* __restrict__ meta,
                                                        u32* __restrict__ keysT) {
  __shared__ u32 tile[64][65];
  const u32 isbf = meta[0];
  const int c0 = blockIdx.x * 64, n0 = blockIdx.y * 64, b = blockIdx.z;
  const int tj = threadIdx.x & 63, t4 = threadIdx.x >> 6;
  const u16* inh = (const u16*)inv;
  const float* inf_ = (const float*)inv;
#pragma unroll
  for (int kk = 0; kk < 16; ++kk) {
    const int i = t4 + kk * 4;
    const int n = n0 + i, c = c0 + tj;
    u32 kx = 0;
    if (n < NA && c < NC) {
      const size_t idx = (size_t)(b * NA + n) * ND + 1 + c;
      const float f = isbf ? bf2f(inh[idx]) : inf_[idx];
      kx = (f > CONF) ? __float_as_uint(f) : 0u;
    }
    tile[i][tj] = kx;
  }
  __syncthreads();
#pragma unroll
  for (int kk = 0; kk < 16; ++kk) {
    const int j = t4 + kk * 4;
    const int c = c0 + j, n = n0 + tj;
    if (c < NC && n < NA) keysT[(size_t)(b * NC + c) * NA + n] = tile[tj][j];
  }
}

// per-(b,c): exact stable top-300 via LDS-histogram superset + full-composite bitonic
// sort (radix fallback only if superset > 512). Writes the 300 sorted (descending)
// composites ((key<<14)|(16383-n)) to candws[bc*300 + rank]. NO NMS here.
__global__ __launch_bounds__(256) void k_select(const void* __restrict__ inv,
                                                const u32* __restrict__ meta,
                                                u64* __restrict__ candws,
                                                const u32* __restrict__ keysT,
                                                const int use_keys) {
  const int bc = blockIdx.x;
  const int b = bc / NC;
  const int c = bc - b * NC;
  const int tid = threadIdx.x;
  const int lane = tid & 63;
  const int wid = tid >> 6;

  __shared__ u32 wsum[4];
  __shared__ u64 cand[512];
  __shared__ u32 shist[256];
  __shared__ u32 sh_cnt, sh_B;

  const u32 isbf = meta[0];

  u32 key[36];
  if (use_keys) {
    const uint4* col4 = (const uint4*)(keysT + (size_t)(b * NC + c) * NA);
#pragma unroll
    for (int r = 0; r < 9; ++r) {
      const int i4 = r * 256 + tid;
      if (i4 < NA4) {
        const uint4 k4 = col4[i4];
        key[r * 4 + 0] = k4.x; key[r * 4 + 1] = k4.y;
        key[r * 4 + 2] = k4.z; key[r * 4 + 3] = k4.w;
      } else {
        key[r * 4 + 0] = 0; key[r * 4 + 1] = 0; key[r * 4 + 2] = 0; key[r * 4 + 3] = 0;
      }
    }
  } else if (isbf) {
    const u16* basep = (const u16*)inv + (size_t)b * NA * ND + 1 + c;
#pragma unroll
    for (int r = 0; r < 9; ++r) {
      const int i4 = r * 256 + tid;
#pragma unroll
      for (int kk = 0; kk < 4; ++kk) {
        u32 kx = 0;
        if (i4 < NA4) {
          const float f = bf2f(basep[(size_t)(i4 * 4 + kk) * ND]);
          kx = (f > CONF) ? __float_as_uint(f) : 0u;
        }
        key[r * 4 + kk] = kx;
      }
    }
  } else {
    const float* basep = (const float*)inv + (size_t)b * NA * ND + 1 + c;
#pragma unroll
    for (int r = 0; r < 9; ++r) {
      const int i4 = r * 256 + tid;
#pragma unroll
      for (int kk = 0; kk < 4; ++kk) {
        u32 kx = 0;
        if (i4 < NA4) {
          const float f = basep[(size_t)(i4 * 4 + kk) * ND];
          kx = (f > CONF) ? __float_as_uint(f) : 0u;
        }
        key[r * 4 + kk] = kx;
      }
    }
  }

  // LDS histogram over coarse score bins; threshold bin B with cum >= 300
  shist[tid] = 0;
  if (tid == 0) { sh_cnt = 0; sh_B = 0; }
  cand[tid] = 0; cand[tid + 256] = 0;
  __syncthreads();
#pragma unroll
  for (int e = 0; e < 36; ++e) atomicAdd(&shist[bin8(key[e])], 1u);
  __syncthreads();
  if (tid == 0) {
    u32 acc = 0, B = 0;
    for (int t = 255; t >= 0; --t) {
      acc += shist[t];
      if (acc >= (u32)NM) { B = (u32)t; break; }
    }
    sh_B = B;
  }
  __syncthreads();
  const u32 B = sh_B;

  // superset collect (score dominates composite ordering => contains all top-300)
#pragma unroll
  for (int r = 0; r < 9; ++r) {
#pragma unroll
    for (int kk = 0; kk < 4; ++kk) {
      const u32 k = key[r * 4 + kk];
      if (bin8(k) >= B) {
        const u32 nn = 16383u - (u32)((r * 256 + tid) * 4 + kk);
        const u32 p = atomicAdd(&sh_cnt, 1u);
        if (p < 512) cand[p] = (((u64)k) << 14) | (u64)nn;
      }
    }
  }
  __syncthreads();

  if (sh_cnt > 512) {
    // fallback: exact radix for the 300th composite, then exact collect
    auto blockSum = [&](u32 v) -> u32 {
#pragma unroll
      for (int off = 32; off > 0; off >>= 1) v += __shfl_down(v, off, 64);
      if (lane == 0) wsum[wid] = v;
      __syncthreads();
      const u32 tot = wsum[0] + wsum[1] + wsum[2] + wsum[3];
      __syncthreads();
      return tot;
    };
    u64 T = T_PRESET;
#pragma unroll 1
    for (int bit = 39; bit >= 0; --bit) {
      if (isbf && bit >= 14 && bit < 30) continue;
      const u64 T2 = T | (1ull << bit);
      const u32 Thi = (u32)(T2 >> 14);
      const u32 Tlo = (u32)(T2 & 0x3FFFu);
      u32 cnt = 0;
#pragma unroll
      for (int r = 0; r < 9; ++r) {
#pragma unroll
        for (int kk = 0; kk < 4; ++kk) {
          const u32 k = key[r * 4 + kk];
          const u32 nn = 16383u - (u32)((r * 256 + tid) * 4 + kk);
          cnt += (k > Thi || (k == Thi && nn >= Tlo)) ? 1u : 0u;
        }
      }
      if (blockSum(cnt) >= NM) T = T2;
    }
    if (tid == 0) sh_cnt = 0;
    cand[tid] = 0; cand[tid + 256] = 0;
    __syncthreads();
    const u32 Thi = (u32)(T >> 14);
    const u32 Tlo = (u32)(T & 0x3FFFu);
#pragma unroll
    for (int r = 0; r < 9; ++r) {
#pragma unroll
      for (int kk = 0; kk < 4; ++kk) {
        const u32 k = key[r * 4 + kk];
        const u32 nn = 16383u - (u32)((r * 256 + tid) * 4 + kk);
        if (k > Thi || (k == Thi && nn >= Tlo)) {
          const u32 p = atomicAdd(&sh_cnt, 1u);
          if (p < 512) cand[p] = (((u64)k) << 14) | (u64)nn;
        }
      }
    }
    __syncthreads();
  }

  // bitonic ascending sort; top-300 land at 511..212
#pragma unroll 1
  for (u32 ks = 2; ks <= 512; ks <<= 1) {
#pragma unroll 1
    for (u32 j = ks >> 1; j > 0; j >>= 1) {
#pragma unroll
      for (int rep = 0; rep < 2; ++rep) {
        const u32 i = tid + rep * 256;
        const u32 ixj = i ^ j;
        if (ixj > i) {
          const u64 a = cand[i], bb = cand[ixj];
          const bool up = ((i & ks) == 0);
          if (up ? (a > bb) : (a < bb)) { cand[i] = bb; cand[ixj] = a; }
        }
      }
      __syncthreads();
    }
  }

  // write descending top-300 composites
  u64* cw = candws + (size_t)bc * NM;
  if (tid < NM) cw[tid] = cand[511 - tid];
  if (tid < NM - 256) cw[256 + tid] = cand[511 - 256 - tid];
}

// one wave per (b,c): BITMASK greedy NMS.
// Phase 1 (throughput): each lane computes, for its 5 column-candidates j, the
// suppression bit-matrix column (bit i = "keeper i would suppress j"), identical
// _rn float op order as the reference's precomputed supmat -- no cross-lane ops,
// latency fully pipelined. Phase 2 (serial): greedy walk using only ballot +
// register bit ops on the chain (~30 cy/keeper) -- no shuffles, no divides.
__global__ __launch_bounds__(64) void k_nms(const void* __restrict__ inv,
                                            const u32* __restrict__ meta,
                                            u64* __restrict__ candws,
                                            u32* __restrict__ hist) {
  const int bc = blockIdx.x;
  const int b = bc / NC;
  const int c = bc - b * NC;
  const int lane = threadIdx.x;
  const u32 isbf = meta[0];
  u64* cw = candws + (size_t)bc * NM;

  __shared__ float4 sbox[NM];   // (y0, x0, y1, x1)
  __shared__ float  sarea[NM];

  float by0[5], bx0[5], by1[5], bx1[5], bar[5], bv[5];
  u32 bn[5];
  bool sup[5], keep[5];

  // load candidates, build register boxes + LDS staging
#pragma unroll
  for (int q = 0; q < 5; ++q) {
    const int j = q * 64 + lane;
    keep[q] = false;
    sup[q] = false;
    by0[q] = bx0[q] = by1[q] = bx1[q] = bar[q] = 0.f;
    if (j < NM) {
      const u64 e = cw[j];
      const u32 sb = (u32)(e >> 14);
      u32 n = 16383u - ((u32)e & 0x3FFFu);
      if (n >= (u32)NA) n = 0;      // zero-pad slot
      bn[q] = n;
      bv[q] = __uint_as_float(sb);  // 0.0f for pad/below-conf
      float cx, cy, w, h;
      if (isbf) {
        const u16* bp = (const u16*)inv + (size_t)(b * NA + n) * ND + 600;
        const ushort4 ub = *(const ushort4*)bp;
        cx = bf2f(ub.x); cy = bf2f(ub.y); w = bf2f(ub.z); h = bf2f(ub.w);
      } else {
        const float* bp = (const float*)inv + (size_t)(b * NA + n) * ND + 600;
        const float4 f4 = *(const float4*)bp;
        cx = f4.x; cy = f4.y; w = f4.z; h = f4.w;
      }
      const float y0 = __fsub_rn(cy, __fmul_rn(h, 0.5f));
      const float x0 = __fsub_rn(cx, __fmul_rn(w, 0.5f));
      const float y1 = __fadd_rn(cy, __fmul_rn(h, 0.5f));
      const float x1 = __fadd_rn(cx, __fmul_rn(w, 0.5f));
      by0[q] = y0; bx0[q] = x0; by1[q] = y1; bx1[q] = x1;
      bar[q] = __fmul_rn(__fsub_rn(y1, y0), __fsub_rn(x1, x0));
      sbox[j] = make_float4(y0, x0, y1, x1);
      sarea[j] = bar[q];
    } else {
      bv[q] = 0.f; bn[q] = 0;
    }
  }
  __syncthreads();

  // ---- phase 1: suppression bit matrix, columns in registers ----
  // colbits[q][w]: bit (i - w*64) set iff keeper i would suppress j = q*64+lane.
  u64 colbits[5][5];
#pragma unroll
  for (int q = 0; q < 5; ++q)
#pragma unroll
    for (int w = 0; w < 5; ++w) colbits[q][w] = 0ull;

#pragma unroll
  for (int w = 0; w < 5; ++w) {
    const int ilim = (w == 4) ? (NM - 256) : 64;
    u64 bitm = 1ull;
    float4 ib = sbox[w * 64];
    float ia = sarea[w * 64];
#pragma unroll 1
    for (int bi = 0; bi < ilim; ++bi) {
      const int i = w * 64 + bi;
      const int inext = (i + 1 < NM) ? i + 1 : i;
      const float4 nb = sbox[inext];
      const float na = sarea[inext];
#pragma unroll
      for (int q = 0; q < 5; ++q) {
        if (q >= w) {
          const int j = q * 64 + lane;
          bool cond = false;
          if (j > i && j < NM) {
            const float ihh = fmaxf(__fsub_rn(fminf(ib.z, by1[q]), fmaxf(ib.x, by0[q])), 0.f);
            const float iww = fmaxf(__fsub_rn(fminf(ib.w, bx1[q]), fmaxf(ib.y, bx0[q])), 0.f);
            const float inter = __fmul_rn(ihh, iww);
            const float uni = __fsub_rn(__fadd_rn(ia, bar[q]), inter);
            cond = (uni > 0.f) && (__fdiv_rn(inter, uni) > 0.45f);
          }
          colbits[q][w] |= cond ? bitm : 0ull;
        }
      }
      bitm <<= 1;
      ib = nb; ia = na;
    }
  }

  // ---- phase 2: greedy walk, ballot + bit ops only ----
#pragma unroll
  for (int qi = 0; qi < 5; ++qi) {
    const int lim = (qi == 4) ? (NM - 256) : 64;
    const bool inlim = (lane < lim);
    const bool conf_ok = (bv[qi] > CONF);
    int pp = 0;
#pragma unroll 1
    while (true) {
      const bool el = inlim && conf_ok && !sup[qi] && (lane >= pp);
      const u64 m = __ballot(el);
      if (m == 0) break;
      const int li = (int)(__ffsll((unsigned long long)m)) - 1;  // next keeper
      if (lane == li) keep[qi] = true;
#pragma unroll
      for (int q = 0; q < 5; ++q) {
        if (q >= qi)   // bits for q<qi are never set (j<i there)
          sup[q] = sup[q] || (((colbits[q][qi] >> li) & 1ull) != 0ull);
      }
      pp = li + 1;
    }
  }

  // in-place write-back (block owns its slice; reads happened above)
#pragma unroll
  for (int q = 0; q < 5; ++q) {
    const int j = q * 64 + lane;
    if (j < NM) {
      u64 entry = 0;
      if (keep[q]) {
        const u32 sb = __float_as_uint(bv[q]);
        const u32 flat = (u32)c * NM + (u32)j;
        entry = (((u64)sb) << 32) | (((u64)(0x3FFFFu - flat)) << 14) | (u64)bn[q];
        atomicAdd(&hist[(size_t)b * NBIN + binTop(sb)], 1u);
      }
      cw[j] = entry;
    }
  }
}

// compute per-batch bin threshold B (cum >= 200 scanning from highest scores);
// also zero the collect counters (safe here: keysT is dead after k_select).
__global__ __launch_bounds__(1024) void k_thresh(const u32* __restrict__ hist,
                                                 u32* __restrict__ meta,
                                                 u32* __restrict__ selcnt) {
  __shared__ u32 ps[1024];
  const int tid = threadIdx.x;
  if (tid < NB) selcnt[tid] = 0;
  for (int b = 0; b < NB; ++b) {
    const u32* hh = hist + (size_t)b * NBIN;
    const uint4 hv = ((const uint4*)hh)[tid];
    ps[tid] = hv.x + hv.y + hv.z + hv.w;
    __syncthreads();
    if (tid == 0) {
      u32 acc = 0, B = (u32)(NBIN - 1);
      for (int t = 0; t < 1024; ++t) {
        if (acc + ps[t] >= (u32)NK) {
          u32 a2 = acc;
          for (int jj = 0; jj < 4; ++jj) {
            const u32 cb = hh[t * 4 + jj];
            if (a2 + cb >= (u32)NK) { B = (u32)(t * 4 + jj); break; }
            a2 += cb;
          }
          break;
        }
        acc += ps[t];
      }
      meta[4 + b] = B;   // never reached 200 => NBIN-1 => collect everything
    }
    __syncthreads();
  }
}

// full-chip scan of the kept list; append qualifying entries (~250/batch)
__global__ __launch_bounds__(256) void k_collect(const u64* __restrict__ list,
                                                 const u32* __restrict__ meta,
                                                 u32* __restrict__ selcnt,
                                                 u64* __restrict__ selbuf) {
  const u32 i = blockIdx.x * 256 + threadIdx.x;
  if (i >= (u32)(NB * MT)) return;
  const u32 b = (i < (u32)MT) ? 0u : 1u;
  const u64 e = list[i];
  if (e != 0 && binTop((u32)(e >> 32)) <= meta[4 + b]) {
    const u32 p = atomicAdd(&selcnt[b], 1u);
    if (p < 512) selbuf[(size_t)b * 512 + p] = e;
  }
}

// shared epilogue: corner->center transform + dtype-matched store
__device__ __forceinline__ void emit_row(const void* inv, u32 isbf, int b, int tid,
                                         u64 e, void* outv) {
  float o0 = 0, o1 = 0, o2 = 0, o3 = 0, o4 = 0, o5 = 0;
  if (e != 0) {
    const u32 sb = (u32)(e >> 32);
    const u32 flat = 0x3FFFFu - ((u32)(e >> 14) & 0x3FFFFu);
    const u32 anchor = (u32)e & 0x3FFFu;
    const u32 cls = flat / NM;
    float cx, cy, w, h;
    if (isbf) {
      const u16* bp = (const u16*)inv + (size_t)(b * NA + anchor) * ND + 600;
      const ushort4 ub = *(const ushort4*)bp;
      cx = bf2f(ub.x); cy = bf2f(ub.y); w = bf2f(ub.z); h = bf2f(ub.w);
    } else {
      const float* bp = (const float*)inv + (size_t)(b * NA + anchor) * ND + 600;
      const float4 f4 = *(const float4*)bp;
      cx = f4.x; cy = f4.y; w = f4.z; h = f4.w;
    }
    const float y0 = __fsub_rn(cy, __fmul_rn(h, 0.5f));
    const float x0 = __fsub_rn(cx, __fmul_rn(w, 0.5f));
    const float y1 = __fadd_rn(cy, __fmul_rn(h, 0.5f));
    const float x1 = __fadd_rn(cx, __fmul_rn(w, 0.5f));
    const float th = __fsub_rn(y1, y0), tw = __fsub_rn(x1, x0);
    o0 = (float)(cls + 1);
    o1 = __uint_as_float(sb);
    o2 = __fadd_rn(x0, __fmul_rn(tw, 0.5f));
    o3 = __fadd_rn(y0, __fmul_rn(th, 0.5f));
    o4 = tw;
    o5 = th;
  }
  if (isbf) {
    __hip_bfloat16* op = (__hip_bfloat16*)outv + ((size_t)b * NK + tid) * 6;
    op[0] = __float2bfloat16(o0); op[1] = __float2bfloat16(o1);
    op[2] = __float2bfloat16(o2); op[3] = __float2bfloat16(o3);
    op[4] = __float2bfloat16(o4); op[5] = __float2bfloat16(o5);
  } else {
    float* op = (float*)outv + ((size_t)b * NK + tid) * 6;
    op[0] = o0; op[1] = o1; op[2] = o2; op[3] = o3; op[4] = o4; op[5] = o5;
  }
}

// per batch: sort <=512 collected entries, emit top-200 (radix fallback if overflow)
__global__ __launch_bounds__(1024) void k_out(const void* __restrict__ inv,
                                              const u32* __restrict__ meta,
                                              const u64* __restrict__ list,
                                              const u32* __restrict__ selcnt,
                                              const u64* __restrict__ selbuf,
                                              void* __restrict__ outv) {
  const int b = blockIdx.x, tid = threadIdx.x, lane = tid & 63, wid = tid >> 6;
  const u32 isbf = meta[0];
  const u64* lb = list + (size_t)b * MT;

  __shared__ u64 sel[512];
  __shared__ u32 wsum[16];
  __shared__ u32 sh_cc;

  const u32 cc0 = selcnt[b];
  if (cc0 <= 512) {
    if (tid < 512) sel[tid] = (tid < (int)cc0) ? selbuf[(size_t)b * 512 + tid] : 0;
    __syncthreads();
  } else {
    // pathological overflow: exact radix fallback over the full list
    if (tid == 0) sh_cc = 0;
    __syncthreads();
    auto bsum = [&](u32 v) -> u32 {
#pragma unroll
      for (int off = 32; off > 0; off >>= 1) v += __shfl_down(v, off, 64);
      if (lane == 0) wsum[wid] = v;
      __syncthreads();
      u32 t = 0;
#pragma unroll
      for (int wq = 0; wq < 16; ++wq) t += wsum[wq];
      __syncthreads();
      return t;
    };
    u64 T = 0;
#pragma unroll 1
    for (int bit = 47; bit >= 0; --bit) {
      if (isbf && bit >= 18 && bit < 34) continue;
      const u64 T2 = T | (1ull << bit);
      u32 cn = 0;
      for (u32 i = tid; i < (u32)MT; i += 1024) {
        const u64 e = lb[i];
        cn += (e != 0 && (e >> 14) >= T2) ? 1u : 0u;
      }
      if (bsum(cn) >= (u32)NK) T = T2;
    }
    for (u32 i = tid; i < (u32)MT; i += 1024) {
      const u64 e = lb[i];
      if (e != 0 && (e >> 14) >= T) {
        const u32 p = atomicAdd(&sh_cc, 1u);
        if (p < 512) sel[p] = e;
      }
    }
    __syncthreads();
    const u32 cc = sh_cc;
    for (u32 p = cc + tid; p < 512; p += 1024) sel[p] = 0;
    __syncthreads();
  }

#pragma unroll 1
  for (u32 ks = 2; ks <= 512; ks <<= 1) {
#pragma unroll 1
    for (u32 j = ks >> 1; j > 0; j >>= 1) {
      if (tid < 512) {
        const u32 i = (u32)tid, ixj = i ^ j;
        if (ixj > i) {
          const u64 a = sel[i], c2 = sel[ixj];
          const bool up = ((i & ks) == 0);
          if (up ? (a > c2) : (a < c2)) { sel[i] = c2; sel[ixj] = a; }
        }
      }
      __syncthreads();
    }
  }

  if (tid < NK) emit_row(inv, isbf, b, tid, sel[511 - tid], outv);
}

extern "C" void kernel_launch(void* const* d_in, const int* in_sizes, int n_in,
                              void* d_out, int out_size, void* d_ws, size_t ws_size,
                              hipStream_t stream) {
  (void)in_sizes; (void)n_in; (void)out_size;
  const void* in = d_in[0];
  char* ws = (char*)d_ws;

  // layout: meta u32[8] @0 (32) | hist u32[2*4096] @32 (32,768) ->32,800
  //         cand/list u64[2*MT] @32,800 (2,875,200) ->2,908,000
  //         keysT u32[2*NC*NA] @2,908,000 (41,843,744) ->44,751,744
  //         selcnt/selbuf OVERLAY keysT @2,908,000: keysT dead after k_select;
  //         selcnt zeroed by k_thresh (post-select) -> timeline-safe.
  u32* meta   = (u32*)ws;
  u32* hist   = (u32*)(ws + 32);
  u64* candws = (u64*)(ws + 32800);
  u32* keysT  = (u32*)(ws + 2908000);
  u32* selcnt = (u32*)(ws + 2908000);
  u64* selbuf = (u64*)(ws + 2908064);
  const bool tier1 = ws_size >= 44751744u;   // coalesced key transpose enabled

  hipLaunchKernelGGL(k_detect, dim3(1), dim3(256), 0, stream, (const u16*)in, meta, hist);
  if (tier1) {
    hipLaunchKernelGGL(k_transpose_keys, dim3(10, 137, 2), dim3(256), 0, stream,
                       in, meta, keysT);
  }
  hipLaunchKernelGGL(k_select, dim3(NB * NC), dim3(256), 0, stream,
                     in, meta, candws, keysT, tier1 ? 1 : 0);
  hipLaunchKernelGGL(k_nms, dim3(NB * NC), dim3(64), 0, stream,
                     in, meta, candws, hist);
  hipLaunchKernelGGL(k_thresh, dim3(1), dim3(1024), 0, stream, hist, meta, selcnt);
  hipLaunchKernelGGL(k_collect, dim3((NB * MT + 255) / 256), dim3(256), 0, stream,
                     candws, meta, selcnt, selbuf);
  hipLaunchKernelGGL(k_out, dim3(NB), dim3(1024), 0, stream,
                     in, meta, candws, selcnt, selbuf, d_out);
}

// Round 11
// 249.486 us; speedup vs baseline: 1.2831x; 1.2831x over previous
//
#include <hip/hip_runtime.h>
#include <hip/hip_bf16.h>
#include <stdint.h>

typedef unsigned short u16;
typedef uint32_t u32;
typedef uint64_t u64;

#define NB 2
#define NA 8732
#define ND 604
#define NC 599
#define NM 300
#define NK 200
#define MT (NC * NM)     // 179700
#define NA4 (NA / 4)     // 2183
#define CONF 0.01f
#define NBIN 4096

#define T_PRESET (0xFull << 40)

__device__ __forceinline__ float bf2f(u16 u) { return __uint_as_float(((u32)u) << 16); }

// global top-k bin: fine resolution near s=1 (kept scores concentrate in (0.966,1)).
// bin ASCENDS as score DESCENDS.
__device__ __forceinline__ u32 binTop(u32 sbits) {
  const float t = __fsub_rn(1.0f, __uint_as_float(sbits));
  const float u = __fmul_rn(t, 65536.0f);
  u32 bin = (u32)u;
  return bin > (NBIN - 1) ? (NBIN - 1) : bin;
}

// per-class coarse score bin (ascending in score)
__device__ __forceinline__ u32 bin8(u32 kbits) {
  u32 bin = (u32)__fmul_rn(__uint_as_float(kbits), 256.0f);
  return bin > 255 ? 255 : bin;
}

// meta[0] = input storage is true-bf16. Also zeroes the per-batch score histogram.
__global__ void k_detect(const u16* __restrict__ in, u32* __restrict__ meta,
                         u32* __restrict__ hist) {
  __shared__ u32 ws4[4], wz4[4];
  const int tid = threadIdx.x, lane = tid & 63, wid = tid >> 6;
  u32 ct = 0, cz = 0;
  for (int i = tid; i < 8192; i += 256) {
    const u16 v = in[i];
    ct += (u32)(v >> 15);
    cz += (u32)(((i & 1) == 0) && (v == 0));
  }
  for (int i = tid; i < NB * NBIN; i += 256) hist[i] = 0u;
#pragma unroll
  for (int off = 32; off > 0; off >>= 1) {
    ct += __shfl_down(ct, off, 64);
    cz += __shfl_down(cz, off, 64);
  }
  if (lane == 0) { ws4[wid] = ct; wz4[wid] = cz; }
  __syncthreads();
  if (tid == 0) {
    const u32 tot_top = ws4[0] + ws4[1] + ws4[2] + ws4[3];
    const u32 tot_evz = wz4[0] + wz4[1] + wz4[2] + wz4[3];
    meta[0] = (tot_top == 0 && tot_evz < 1024) ? 1u : 0u;  // else f32 storage
    meta[1] = 0u; meta[2] = 0u; meta[3] = 0u;
  }
}

// tiled transpose of class scores -> thresholded u32 keys [b][c][n]
__global__ __launch_bounds__(256) void k_transpose_keys(const void* __restrict__ inv,
                                                        const u32* __restrict__ meta,
                                                        u32* __restrict__ keysT) {
  __shared__ u32 tile[64][65];
  const u32 isbf = meta[0];
  const int c0 = blockIdx.x * 64, n0 = blockIdx.y * 64, b = blockIdx.z;
  const int tj = threadIdx.x & 63, t4 = threadIdx.x >> 6;
  const u16* inh = (const u16*)inv;
  const float* inf_ = (const float*)inv;
#pragma unroll
  for (int kk = 0; kk < 16; ++kk) {
    const int i = t4 + kk * 4;
    const int n = n0 + i, c = c0 + tj;
    u32 kx = 0;
    if (n < NA && c < NC) {
      const size_t idx = (size_t)(b * NA + n) * ND + 1 + c;
      const float f = isbf ? bf2f(inh[idx]) : inf_[idx];
      kx = (f > CONF) ? __float_as_uint(f) : 0u;
    }
    tile[i][tj] = kx;
  }
  __syncthreads();
#pragma unroll
  for (int kk = 0; kk < 16; ++kk) {
    const int j = t4 + kk * 4;
    const int c = c0 + j, n = n0 + tj;
    if (c < NC && n < NA) keysT[(size_t)(b * NC + c) * NA + n] = tile[tj][j];
  }
}

// per-(b,c): exact stable top-300 via LDS-histogram superset + full-composite bitonic
// sort (radix fallback only if superset > 512). Writes the 300 sorted (descending)
// composites ((key<<14)|(16383-n)) to candws[bc*300 + rank]. NO NMS here.
__global__ __launch_bounds__(256) void k_select(const void* __restrict__ inv,
                                                const u32* __restrict__ meta,
                                                u64* __restrict__ candws,
                                                const u32* __restrict__ keysT,
                                                const int use_keys) {
  const int bc = blockIdx.x;
  const int b = bc / NC;
  const int c = bc - b * NC;
  const int tid = threadIdx.x;
  const int lane = tid & 63;
  const int wid = tid >> 6;

  __shared__ u32 wsum[4];
  __shared__ u64 cand[512];
  __shared__ u32 shist[256];
  __shared__ u32 sh_cnt, sh_B;

  const u32 isbf = meta[0];

  u32 key[36];
  if (use_keys) {
    const uint4* col4 = (const uint4*)(keysT + (size_t)(b * NC + c) * NA);
#pragma unroll
    for (int r = 0; r < 9; ++r) {
      const int i4 = r * 256 + tid;
      if (i4 < NA4) {
        const uint4 k4 = col4[i4];
        key[r * 4 + 0] = k4.x; key[r * 4 + 1] = k4.y;
        key[r * 4 + 2] = k4.z; key[r * 4 + 3] = k4.w;
      } else {
        key[r * 4 + 0] = 0; key[r * 4 + 1] = 0; key[r * 4 + 2] = 0; key[r * 4 + 3] = 0;
      }
    }
  } else if (isbf) {
    const u16* basep = (const u16*)inv + (size_t)b * NA * ND + 1 + c;
#pragma unroll
    for (int r = 0; r < 9; ++r) {
      const int i4 = r * 256 + tid;
#pragma unroll
      for (int kk = 0; kk < 4; ++kk) {
        u32 kx = 0;
        if (i4 < NA4) {
          const float f = bf2f(basep[(size_t)(i4 * 4 + kk) * ND]);
          kx = (f > CONF) ? __float_as_uint(f) : 0u;
        }
        key[r * 4 + kk] = kx;
      }
    }
  } else {
    const float* basep = (const float*)inv + (size_t)b * NA * ND + 1 + c;
#pragma unroll
    for (int r = 0; r < 9; ++r) {
      const int i4 = r * 256 + tid;
#pragma unroll
      for (int kk = 0; kk < 4; ++kk) {
        u32 kx = 0;
        if (i4 < NA4) {
          const float f = basep[(size_t)(i4 * 4 + kk) * ND];
          kx = (f > CONF) ? __float_as_uint(f) : 0u;
        }
        key[r * 4 + kk] = kx;
      }
    }
  }

  // LDS histogram over coarse score bins; threshold bin B with cum >= 300
  shist[tid] = 0;
  if (tid == 0) { sh_cnt = 0; sh_B = 0; }
  cand[tid] = 0; cand[tid + 256] = 0;
  __syncthreads();
#pragma unroll
  for (int e = 0; e < 36; ++e) atomicAdd(&shist[bin8(key[e])], 1u);
  __syncthreads();
  if (tid == 0) {
    u32 acc = 0, B = 0;
    for (int t = 255; t >= 0; --t) {
      acc += shist[t];
      if (acc >= (u32)NM) { B = (u32)t; break; }
    }
    sh_B = B;
  }
  __syncthreads();
  const u32 B = sh_B;

  // superset collect (score dominates composite ordering => contains all top-300)
#pragma unroll
  for (int r = 0; r < 9; ++r) {
#pragma unroll
    for (int kk = 0; kk < 4; ++kk) {
      const u32 k = key[r * 4 + kk];
      if (bin8(k) >= B) {
        const u32 nn = 16383u - (u32)((r * 256 + tid) * 4 + kk);
        const u32 p = atomicAdd(&sh_cnt, 1u);
        if (p < 512) cand[p] = (((u64)k) << 14) | (u64)nn;
      }
    }
  }
  __syncthreads();

  if (sh_cnt > 512) {
    // fallback: exact radix for the 300th composite, then exact collect
    auto blockSum = [&](u32 v) -> u32 {
#pragma unroll
      for (int off = 32; off > 0; off >>= 1) v += __shfl_down(v, off, 64);
      if (lane == 0) wsum[wid] = v;
      __syncthreads();
      const u32 tot = wsum[0] + wsum[1] + wsum[2] + wsum[3];
      __syncthreads();
      return tot;
    };
    u64 T = T_PRESET;
#pragma unroll 1
    for (int bit = 39; bit >= 0; --bit) {
      if (isbf && bit >= 14 && bit < 30) continue;
      const u64 T2 = T | (1ull << bit);
      const u32 Thi = (u32)(T2 >> 14);
      const u32 Tlo = (u32)(T2 & 0x3FFFu);
      u32 cnt = 0;
#pragma unroll
      for (int r = 0; r < 9; ++r) {
#pragma unroll
        for (int kk = 0; kk < 4; ++kk) {
          const u32 k = key[r * 4 + kk];
          const u32 nn = 16383u - (u32)((r * 256 + tid) * 4 + kk);
          cnt += (k > Thi || (k == Thi && nn >= Tlo)) ? 1u : 0u;
        }
      }
      if (blockSum(cnt) >= NM) T = T2;
    }
    if (tid == 0) sh_cnt = 0;
    cand[tid] = 0; cand[tid + 256] = 0;
    __syncthreads();
    const u32 Thi = (u32)(T >> 14);
    const u32 Tlo = (u32)(T & 0x3FFFu);
#pragma unroll
    for (int r = 0; r < 9; ++r) {
#pragma unroll
      for (int kk = 0; kk < 4; ++kk) {
        const u32 k = key[r * 4 + kk];
        const u32 nn = 16383u - (u32)((r * 256 + tid) * 4 + kk);
        if (k > Thi || (k == Thi && nn >= Tlo)) {
          const u32 p = atomicAdd(&sh_cnt, 1u);
          if (p < 512) cand[p] = (((u64)k) << 14) | (u64)nn;
        }
      }
    }
    __syncthreads();
  }

  // bitonic ascending sort; top-300 land at 511..212
#pragma unroll 1
  for (u32 ks = 2; ks <= 512; ks <<= 1) {
#pragma unroll 1
    for (u32 j = ks >> 1; j > 0; j >>= 1) {
#pragma unroll
      for (int rep = 0; rep < 2; ++rep) {
        const u32 i = tid + rep * 256;
        const u32 ixj = i ^ j;
        if (ixj > i) {
          const u64 a = cand[i], bb = cand[ixj];
          const bool up = ((i & ks) == 0);
          if (up ? (a > bb) : (a < bb)) { cand[i] = bb; cand[ixj] = a; }
        }
      }
      __syncthreads();
    }
  }

  // write descending top-300 composites
  u64* cw = candws + (size_t)bc * NM;
  if (tid < NM) cw[tid] = cand[511 - tid];
  if (tid < NM - 256) cw[256 + tid] = cand[511 - 256 - tid];
}

// 256 threads per (b,c): BITMASK greedy NMS, division-free.
// Exactness: reference tests fl(inter/uni) > 0.45f. With t = midpoint of
// [0.45f, nextafterf(0.45f)] (0.45f mantissa is even, ties round back to 0.45f),
// that is equivalent to inter/uni > t strictly, i.e. (double)inter > t*(double)uni
// -- and t (25 mantissa bits) times uni (24 bits) is EXACT in double (49 <= 53),
// so the double compare reproduces the correctly-rounded-division compare bit-exactly.
// Phase 1: 4 waves compute bit-matrix slices (wave w handles source chunk w; wave 0
// also the 44-row tail) into LDS -- pure pipelined VALU, no divides, no cross-lane.
// Phase 2: wave 0 greedy walk with ballot + register bit ops only.
__global__ __launch_bounds__(256, 1) void k_nms(const void* __restrict__ inv,
                                                const u32* __restrict__ meta,
                                                u64* __restrict__ candws,
                                                u32* __restrict__ hist) {
  const int bc = blockIdx.x;
  const int b = bc / NC;
  const int c = bc - b * NC;
  const int tid = threadIdx.x;
  const int lane = tid & 63;
  const int wv = tid >> 6;
  const u32 isbf = meta[0];
  u64* cw = candws + (size_t)bc * NM;

  __shared__ float4 sbox[NM];   // (y0, x0, y1, x1)
  __shared__ float  sarea[NM];
  __shared__ float  sv[NM];
  __shared__ u32    sn[NM];
  __shared__ u64    sbits[5][5][64];   // [src chunk w][col chunk q][lane]

  // cooperative load of all 300 candidates
  for (int j = tid; j < NM; j += 256) {
    const u64 e = cw[j];
    const u32 sb = (u32)(e >> 14);
    u32 n = 16383u - ((u32)e & 0x3FFFu);
    if (n >= (u32)NA) n = 0;      // zero-pad slot
    float cx, cy, w, h;
    if (isbf) {
      const u16* bp = (const u16*)inv + (size_t)(b * NA + n) * ND + 600;
      const ushort4 ub = *(const ushort4*)bp;
      cx = bf2f(ub.x); cy = bf2f(ub.y); w = bf2f(ub.z); h = bf2f(ub.w);
    } else {
      const float* bp = (const float*)inv + (size_t)(b * NA + n) * ND + 600;
      const float4 f4 = *(const float4*)bp;
      cx = f4.x; cy = f4.y; w = f4.z; h = f4.w;
    }
    const float y0 = __fsub_rn(cy, __fmul_rn(h, 0.5f));
    const float x0 = __fsub_rn(cx, __fmul_rn(w, 0.5f));
    const float y1 = __fadd_rn(cy, __fmul_rn(h, 0.5f));
    const float x1 = __fadd_rn(cx, __fmul_rn(w, 0.5f));
    sbox[j] = make_float4(y0, x0, y1, x1);
    sarea[j] = __fmul_rn(__fsub_rn(y1, y0), __fsub_rn(x1, x0));
    sv[j] = __uint_as_float(sb);
    sn[j] = n;
  }
  __syncthreads();

  // per-lane column boxes
  float jy0[5], jx0[5], jy1[5], jx1[5], jar[5];
#pragma unroll
  for (int q = 0; q < 5; ++q) {
    const int j = q * 64 + lane;
    if (j < NM) {
      const float4 bb = sbox[j];
      jy0[q] = bb.x; jx0[q] = bb.y; jy1[q] = bb.z; jx1[q] = bb.w;
      jar[q] = sarea[j];
    } else {
      jy0[q] = jx0[q] = jy1[q] = jx1[q] = jar[q] = 0.f;
    }
  }

  const double T45 = ((double)0.45f) + 0x1p-26;  // exact rounding-boundary midpoint

#pragma unroll 1
  for (int pass = 0; pass < 2; ++pass) {
    if (pass == 1 && wv != 0) break;
    const int w = (pass == 0) ? wv : 4;
    const int ilim = (w == 4) ? (NM - 256) : 64;
    u64 acc[5] = {0ull, 0ull, 0ull, 0ull, 0ull};
#pragma unroll 1
    for (int bi = 0; bi < ilim; ++bi) {
      const int i = w * 64 + bi;
      const float4 ib = sbox[i];   // broadcast
      const float ia = sarea[i];
      const u64 bitm = 1ull << bi;
#pragma unroll
      for (int q = 0; q < 5; ++q) {
        const int j = q * 64 + lane;
        bool cond = false;
        if (q >= w && j > i && j < NM) {
          const float ih = fmaxf(__fsub_rn(fminf(ib.z, jy1[q]), fmaxf(ib.x, jy0[q])), 0.f);
          const float iw2 = fmaxf(__fsub_rn(fminf(ib.w, jx1[q]), fmaxf(ib.y, jx0[q])), 0.f);
          const float inter = __fmul_rn(ih, iw2);
          const float uni = __fsub_rn(__fadd_rn(ia, jar[q]), inter);
          cond = (uni > 0.f) && ((double)inter > T45 * (double)uni);
        }
        if (cond) acc[q] |= bitm;
      }
    }
#pragma unroll
    for (int q = 0; q < 5; ++q)
      if (q >= w) sbits[w][q][lane] = acc[q];
  }
  __syncthreads();

  // phase 2: wave 0 greedy walk
  if (tid < 64) {
    u64 col[5][5];
#pragma unroll
    for (int w = 0; w < 5; ++w)
#pragma unroll
      for (int q = 0; q < 5; ++q)
        col[q][w] = (q >= w) ? sbits[w][q][lane] : 0ull;

    float bv[5];
    u32 bn[5];
    bool sup[5], keep[5];
#pragma unroll
    for (int q = 0; q < 5; ++q) {
      const int j = q * 64 + lane;
      keep[q] = false; sup[q] = false;
      bv[q] = (j < NM) ? sv[j] : 0.f;
      bn[q] = (j < NM) ? sn[j] : 0u;
    }

#pragma unroll
    for (int qi = 0; qi < 5; ++qi) {
      const int lim = (qi == 4) ? (NM - 256) : 64;
      const bool inlim = (lane < lim);
      const bool conf_ok = (bv[qi] > CONF);
      int pp = 0;
#pragma unroll 1
      while (true) {
        const bool el = inlim && conf_ok && !sup[qi] && (lane >= pp);
        const u64 m = __ballot(el);
        if (m == 0) break;
        const int li = (int)(__ffsll((unsigned long long)m)) - 1;  // next keeper
        if (lane == li) keep[qi] = true;
#pragma unroll
        for (int q = qi; q < 5; ++q)
          sup[q] = sup[q] || (((col[q][qi] >> li) & 1ull) != 0ull);
        pp = li + 1;
      }
    }

    // in-place write-back
#pragma unroll
    for (int q = 0; q < 5; ++q) {
      const int j = q * 64 + lane;
      if (j < NM) {
        u64 entry = 0;
        if (keep[q]) {
          const u32 sb = __float_as_uint(bv[q]);
          const u32 flat = (u32)c * NM + (u32)j;
          entry = (((u64)sb) << 32) | (((u64)(0x3FFFFu - flat)) << 14) | (u64)bn[q];
          atomicAdd(&hist[(size_t)b * NBIN + binTop(sb)], 1u);
        }
        cw[j] = entry;
      }
    }
  }
}

// compute per-batch bin threshold B (cum >= 200 scanning from highest scores);
// also zero the collect counters (safe here: keysT is dead after k_select).
__global__ __launch_bounds__(1024) void k_thresh(const u32* __restrict__ hist,
                                                 u32* __restrict__ meta,
                                                 u32* __restrict__ selcnt) {
  __shared__ u32 ps[1024];
  const int tid = threadIdx.x;
  if (tid < NB) selcnt[tid] = 0;
  for (int b = 0; b < NB; ++b) {
    const u32* hh = hist + (size_t)b * NBIN;
    const uint4 hv = ((const uint4*)hh)[tid];
    ps[tid] = hv.x + hv.y + hv.z + hv.w;
    __syncthreads();
    if (tid == 0) {
      u32 acc = 0, B = (u32)(NBIN - 1);
      for (int t = 0; t < 1024; ++t) {
        if (acc + ps[t] >= (u32)NK) {
          u32 a2 = acc;
          for (int jj = 0; jj < 4; ++jj) {
            const u32 cb = hh[t * 4 + jj];
            if (a2 + cb >= (u32)NK) { B = (u32)(t * 4 + jj); break; }
            a2 += cb;
          }
          break;
        }
        acc += ps[t];
      }
      meta[4 + b] = B;   // never reached 200 => NBIN-1 => collect everything
    }
    __syncthreads();
  }
}

// full-chip scan of the kept list; append qualifying entries (~250/batch)
__global__ __launch_bounds__(256) void k_collect(const u64* __restrict__ list,
                                                 const u32* __restrict__ meta,
                                                 u32* __restrict__ selcnt,
                                                 u64* __restrict__ selbuf) {
  const u32 i = blockIdx.x * 256 + threadIdx.x;
  if (i >= (u32)(NB * MT)) return;
  const u32 b = (i < (u32)MT) ? 0u : 1u;
  const u64 e = list[i];
  if (e != 0 && binTop((u32)(e >> 32)) <= meta[4 + b]) {
    const u32 p = atomicAdd(&selcnt[b], 1u);
    if (p < 512) selbuf[(size_t)b * 512 + p] = e;
  }
}

// shared epilogue: corner->center transform + dtype-matched store
__device__ __forceinline__ void emit_row(const void* inv, u32 isbf, int b, int tid,
                                         u64 e, void* outv) {
  float o0 = 0, o1 = 0, o2 = 0, o3 = 0, o4 = 0, o5 = 0;
  if (e != 0) {
    const u32 sb = (u32)(e >> 32);
    const u32 flat = 0x3FFFFu - ((u32)(e >> 14) & 0x3FFFFu);
    const u32 anchor = (u32)e & 0x3FFFu;
    const u32 cls = flat / NM;
    float cx, cy, w, h;
    if (isbf) {
      const u16* bp = (const u16*)inv + (size_t)(b * NA + anchor) * ND + 600;
      const ushort4 ub = *(const ushort4*)bp;
      cx = bf2f(ub.x); cy = bf2f(ub.y); w = bf2f(ub.z); h = bf2f(ub.w);
    } else {
      const float* bp = (const float*)inv + (size_t)(b * NA + anchor) * ND + 600;
      const float4 f4 = *(const float4*)bp;
      cx = f4.x; cy = f4.y; w = f4.z; h = f4.w;
    }
    const float y0 = __fsub_rn(cy, __fmul_rn(h, 0.5f));
    const float x0 = __fsub_rn(cx, __fmul_rn(w, 0.5f));
    const float y1 = __fadd_rn(cy, __fmul_rn(h, 0.5f));
    const float x1 = __fadd_rn(cx, __fmul_rn(w, 0.5f));
    const float th = __fsub_rn(y1, y0), tw = __fsub_rn(x1, x0);
    o0 = (float)(cls + 1);
    o1 = __uint_as_float(sb);
    o2 = __fadd_rn(x0, __fmul_rn(tw, 0.5f));
    o3 = __fadd_rn(y0, __fmul_rn(th, 0.5f));
    o4 = tw;
    o5 = th;
  }
  if (isbf) {
    __hip_bfloat16* op = (__hip_bfloat16*)outv + ((size_t)b * NK + tid) * 6;
    op[0] = __float2bfloat16(o0); op[1] = __float2bfloat16(o1);
    op[2] = __float2bfloat16(o2); op[3] = __float2bfloat16(o3);
    op[4] = __float2bfloat16(o4); op[5] = __float2bfloat16(o5);
  } else {
    float* op = (float*)outv + ((size_t)b * NK + tid) * 6;
    op[0] = o0; op[1] = o1; op[2] = o2; op[3] = o3; op[4] = o4; op[5] = o5;
  }
}

// per batch: sort <=512 collected entries, emit top-200 (radix fallback if overflow)
__global__ __launch_bounds__(1024) void k_out(const void* __restrict__ inv,
                                              const u32* __restrict__ meta,
                                              const u64* __restrict__ list,
                                              const u32* __restrict__ selcnt,
                                              const u64* __restrict__ selbuf,
                                              void* __restrict__ outv) {
  const int b = blockIdx.x, tid = threadIdx.x, lane = tid & 63, wid = tid >> 6;
  const u32 isbf = meta[0];
  const u64* lb = list + (size_t)b * MT;

  __shared__ u64 sel[512];
  __shared__ u32 wsum[16];
  __shared__ u32 sh_cc;

  const u32 cc0 = selcnt[b];
  if (cc0 <= 512) {
    if (tid < 512) sel[tid] = (tid < (int)cc0) ? selbuf[(size_t)b * 512 + tid] : 0;
    __syncthreads();
  } else {
    // pathological overflow: exact radix fallback over the full list
    if (tid == 0) sh_cc = 0;
    __syncthreads();
    auto bsum = [&](u32 v) -> u32 {
#pragma unroll
      for (int off = 32; off > 0; off >>= 1) v += __shfl_down(v, off, 64);
      if (lane == 0) wsum[wid] = v;
      __syncthreads();
      u32 t = 0;
#pragma unroll
      for (int wq = 0; wq < 16; ++wq) t += wsum[wq];
      __syncthreads();
      return t;
    };
    u64 T = 0;
#pragma unroll 1
    for (int bit = 47; bit >= 0; --bit) {
      if (isbf && bit >= 18 && bit < 34) continue;
      const u64 T2 = T | (1ull << bit);
      u32 cn = 0;
      for (u32 i = tid; i < (u32)MT; i += 1024) {
        const u64 e = lb[i];
        cn += (e != 0 && (e >> 14) >= T2) ? 1u : 0u;
      }
      if (bsum(cn) >= (u32)NK) T = T2;
    }
    for (u32 i = tid; i < (u32)MT; i += 1024) {
      const u64 e = lb[i];
      if (e != 0 && (e >> 14) >= T) {
        const u32 p = atomicAdd(&sh_cc, 1u);
        if (p < 512) sel[p] = e;
      }
    }
    __syncthreads();
    const u32 cc = sh_cc;
    for (u32 p = cc + tid; p < 512; p += 1024) sel[p] = 0;
    __syncthreads();
  }

#pragma unroll 1
  for (u32 ks = 2; ks <= 512; ks <<= 1) {
#pragma unroll 1
    for (u32 j = ks >> 1; j > 0; j >>= 1) {
      if (tid < 512) {
        const u32 i = (u32)tid, ixj = i ^ j;
        if (ixj > i) {
          const u64 a = sel[i], c2 = sel[ixj];
          const bool up = ((i & ks) == 0);
          if (up ? (a > c2) : (a < c2)) { sel[i] = c2; sel[ixj] = a; }
        }
      }
      __syncthreads();
    }
  }

  if (tid < NK) emit_row(inv, isbf, b, tid, sel[511 - tid], outv);
}

extern "C" void kernel_launch(void* const* d_in, const int* in_sizes, int n_in,
                              void* d_out, int out_size, void* d_ws, size_t ws_size,
                              hipStream_t stream) {
  (void)in_sizes; (void)n_in; (void)out_size;
  const void* in = d_in[0];
  char* ws = (char*)d_ws;

  // layout: meta u32[8] @0 (32) | hist u32[2*4096] @32 (32,768) ->32,800
  //         cand/list u64[2*MT] @32,800 (2,875,200) ->2,908,000
  //         keysT u32[2*NC*NA] @2,908,000 (41,843,744) ->44,751,744
  //         selcnt/selbuf OVERLAY keysT @2,908,000: keysT dead after k_select;
  //         selcnt zeroed by k_thresh (post-select) -> timeline-safe.
  u32* meta   = (u32*)ws;
  u32* hist   = (u32*)(ws + 32);
  u64* candws = (u64*)(ws + 32800);
  u32* keysT  = (u32*)(ws + 2908000);
  u32* selcnt = (u32*)(ws + 2908000);
  u64* selbuf = (u64*)(ws + 2908064);
  const bool tier1 = ws_size >= 44751744u;   // coalesced key transpose enabled

  hipLaunchKernelGGL(k_detect, dim3(1), dim3(256), 0, stream, (const u16*)in, meta, hist);
  if (tier1) {
    hipLaunchKernelGGL(k_transpose_keys, dim3(10, 137, 2), dim3(256), 0, stream,
                       in, meta, keysT);
  }
  hipLaunchKernelGGL(k_select, dim3(NB * NC), dim3(256), 0, stream,
                     in, meta, candws, keysT, tier1 ? 1 : 0);
  hipLaunchKernelGGL(k_nms, dim3(NB * NC), dim3(256), 0, stream,
                     in, meta, candws, hist);
  hipLaunchKernelGGL(k_thresh, dim3(1), dim3(1024), 0, stream, hist, meta, selcnt);
  hipLaunchKernelGGL(k_collect, dim3((NB * MT + 255) / 256), dim3(256), 0, stream,
                     candws, meta, selcnt, selbuf);
  hipLaunchKernelGGL(k_out, dim3(NB), dim3(1024), 0, stream,
                     in, meta, candws, selcnt, selbuf, d_out);
}